// Round 7
// baseline (263.992 us; speedup 1.0000x reference)
//
#include <hip/hip_runtime.h>
#include <math.h>

#define Bn 4
#define Cn 32
#define Dn 64
#define Hn 64
#define Wn 64
#define DHW (Dn * Hn * Wn)      /* 262144 */
#define TOT (Bn * Cn * DHW)     /* 33554432 */
#define NCHUNK 256              /* spatial chunks per batch in reduce */

typedef float f4 __attribute__((ext_vector_type(4)));

// ============================================================
// Kernel 1: fused reductions + tail-block channel-MLP.
//  - per (b, spatial): mean & max over C  -> s_avg, s_max  [B,DHW]
//  - per (b, c, chunk): partials -> part_sum/part_max [B,C,NCHUNK]
//  - LAST block of each batch (atomic counter) reduces partials and runs
//    the 64->128->32 MLP -> ca[B,C].  (once per batch, no extra launch)
// Plain cached loads: NT loads measured 4.5x slower (R6: 420 GB/s, VALU 3.3%).
// ============================================================
__global__ __launch_bounds__(256) void reduce_kernel(
    const float* __restrict__ x,
    float* __restrict__ s_avg, float* __restrict__ s_max,
    float* __restrict__ part_sum, float* __restrict__ part_max,
    unsigned* __restrict__ counter,
    const float* __restrict__ fc1_w, const float* __restrict__ fc1_b,
    const float* __restrict__ fc2_w, const float* __restrict__ fc2_b,
    float* __restrict__ ca) {
    const int b = blockIdx.x / NCHUNK;
    const int chunk = blockIdx.x % NCHUNK;
    const int base = chunk * 1024 + threadIdx.x * 4;
    const int lane = threadIdx.x & 63;
    const int wid = threadIdx.x >> 6;

    f4 ssum = {0.f, 0.f, 0.f, 0.f};
    f4 smax = {-INFINITY, -INFINITY, -INFINITY, -INFINITY};
    float tsum[Cn], tmax[Cn];

    const float* xp = x + (size_t)b * Cn * DHW + base;
#pragma unroll
    for (int c = 0; c < Cn; ++c) {
        const f4 v = *reinterpret_cast<const f4*>(xp + (size_t)c * DHW);
        ssum += v;
        smax.x = fmaxf(smax.x, v.x); smax.y = fmaxf(smax.y, v.y);
        smax.z = fmaxf(smax.z, v.z); smax.w = fmaxf(smax.w, v.w);
        tsum[c] = (v.x + v.y) + (v.z + v.w);
        tmax[c] = fmaxf(fmaxf(v.x, v.y), fmaxf(v.z, v.w));
    }

    const f4 av = ssum * (1.f / Cn);
    *reinterpret_cast<f4*>(s_avg + (size_t)b * DHW + base) = av;
    *reinterpret_cast<f4*>(s_max + (size_t)b * DHW + base) = smax;

    __shared__ float redS[4][Cn];
    __shared__ float redM[4][Cn];
#pragma unroll
    for (int c = 0; c < Cn; ++c) {
        float ps = tsum[c], pm = tmax[c];
#pragma unroll
        for (int off = 32; off; off >>= 1) {
            ps += __shfl_xor(ps, off);
            pm = fmaxf(pm, __shfl_xor(pm, off));
        }
        if (lane == 0) { redS[wid][c] = ps; redM[wid][c] = pm; }
    }
    __syncthreads();
    if (threadIdx.x < Cn) {
        const int c = threadIdx.x;
        float s = (redS[0][c] + redS[1][c]) + (redS[2][c] + redS[3][c]);
        float m = fmaxf(fmaxf(redM[0][c], redM[1][c]),
                        fmaxf(redM[2][c], redM[3][c]));
        part_sum[(b * Cn + c) * NCHUNK + chunk] = s;
        part_max[(b * Cn + c) * NCHUNK + chunk] = m;
    }

    // ---- tail-block detection ----
    __shared__ unsigned done;
    __threadfence();  // make this block's partials device-visible
    if (threadIdx.x == 0) done = atomicAdd(&counter[b], 1u);
    __syncthreads();
    if (done != NCHUNK - 1) return;
    __threadfence();  // acquire: see all other blocks' partials

    // ---- channel-attention MLP (one block per batch) ----
    __shared__ float inp_s[64];
    __shared__ float h_s[128];
    const int t = threadIdx.x;
    if (t < 64) {
        const int which = t >> 5, c = t & 31;
        const f4* p4 = reinterpret_cast<const f4*>(
            (which ? part_max : part_sum) + (b * Cn + c) * NCHUNK);
        if (which == 0) {
            float acc = 0.f;
#pragma unroll
            for (int i = 0; i < NCHUNK / 4; ++i) {
                f4 v = p4[i];
                acc += (v.x + v.y) + (v.z + v.w);
            }
            inp_s[c] = acc * (1.f / DHW);
        } else {
            float m = -INFINITY;
#pragma unroll
            for (int i = 0; i < NCHUNK / 4; ++i) {
                f4 v = p4[i];
                m = fmaxf(m, fmaxf(fmaxf(v.x, v.y), fmaxf(v.z, v.w)));
            }
            inp_s[Cn + c] = m;
        }
    }
    __syncthreads();
    if (t < 128) {
        float acc = fc1_b[t];
#pragma unroll
        for (int k = 0; k < 64; ++k) acc += fc1_w[t * 64 + k] * inp_s[k];
        h_s[t] = fmaxf(acc, 0.f);
    }
    __syncthreads();
    if (t < Cn) {
        float a2 = fc2_b[t];
#pragma unroll
        for (int k = 0; k < 128; ++k) a2 += fc2_w[t * 128 + k] * h_s[k];
        ca[b * Cn + t] = 1.f / (1.f + expf(-a2));
    }
}

// ============================================================
// Kernel 2: conv + epilogue, fused.
//  Tile 64x * 4y * 4z; BOTH input-channel halos resident in LDS (56 KB)
//  -> outputs complete in one pass; 1024 blocks at 2 blocks/CU = two
//  scheduling rounds, so round-2 compute overlaps round-1 store drain.
//  Writes: per (c,oz) combo a wave stores 1KB contiguous x2 streams,
//  nontemporal (no L2 pollution).  (measured ~70 us in R6 - as predicted)
// ============================================================
#define TZc 4
#define TYc 4
#define LXc (Wn + 6)   /* 70 */
#define LYc (TYc + 6)  /* 10 */
#define LZc (TZc + 6)  /* 10 */
#define HALO1 (LZc * LYc * LXc)  /* 7000 */

__global__ __launch_bounds__(256) void conv_kernel(
    const float* __restrict__ ca_g,
    const float* __restrict__ s_avg, const float* __restrict__ s_max,
    const float* __restrict__ w1, const float* __restrict__ w2,
    float* __restrict__ out) {
    __shared__ float sIn[2 * HALO1];          // 56 KB
    __shared__ float sv_s[TZc * TYc * Wn];    // 1024 floats, 4 KB
    __shared__ float ca_s[Cn];

    const int t = threadIdx.x;
    const int bid = blockIdx.x;
    const int b = bid >> 8;            // 256 tiles per batch
    const int tile = bid & 255;
    const int tz = tile >> 4, ty = tile & 15;
    const int z0 = tz * TZc, y0 = ty * TYc;

    if (t < Cn) ca_s[t] = ca_g[b * Cn + t];

    // ---- load both halo buffers ----
    const float* srcA = s_avg + (size_t)b * DHW;
    const float* srcM = s_max + (size_t)b * DHW;
    for (int i = t; i < 2 * HALO1; i += 256) {
        const int ic = i / HALO1;
        const int r0 = i - ic * HALO1;
        const int xx = r0 % LXc;
        const int rem = r0 / LXc;
        const int yy = rem % LYc;
        const int zz = rem / LYc;
        const int gz = z0 + zz - 3, gy = y0 + yy - 3, gx = xx - 3;
        float v = 0.f;
        if ((unsigned)gz < (unsigned)Dn && (unsigned)gy < (unsigned)Hn &&
            (unsigned)gx < (unsigned)Wn)
            v = (ic ? srcM : srcA)[(gz * Hn + gy) * Wn + gx];
        sIn[i] = v;
    }
    __syncthreads();

    // ---- compute: thread (lx, ly) owns full z-column of 4 outputs ----
    const int lx = t & 63, ly = t >> 6;

    float acc[4][TZc];  // [oc][oz]
#pragma unroll
    for (int oc = 0; oc < 4; ++oc)
#pragma unroll
        for (int o = 0; o < TZc; ++o) acc[oc][o] = 0.f;

#pragma unroll 1
    for (int ic = 0; ic < 2; ++ic)
#pragma unroll 1
        for (int kh = 0; kh < 7; ++kh)
#pragma unroll 1
            for (int kw = 0; kw < 7; ++kw) {
                float incol[LZc];
#pragma unroll
                for (int s = 0; s < LZc; ++s)
                    incol[s] = sIn[ic * HALO1 +
                                   (s * LYc + (ly + kh)) * LXc + (lx + kw)];
#pragma unroll
                for (int kd = 0; kd < 7; ++kd)
#pragma unroll
                    for (int oc = 0; oc < 4; ++oc) {
                        // wave-uniform address -> scalar load
                        float w = w1[(((oc * 2 + ic) * 7 + kd) * 7 + kh) * 7 + kw];
#pragma unroll
                        for (int o = 0; o < TZc; ++o)
                            acc[oc][o] += incol[o + kd] * w;
                    }
            }

    const float c20 = w2[0], c21 = w2[1], c22 = w2[2], c23 = w2[3];
#pragma unroll
    for (int o = 0; o < TZc; ++o) {
        float s = fmaxf(acc[0][o], 0.f) * c20 + fmaxf(acc[1][o], 0.f) * c21 +
                  fmaxf(acc[2][o], 0.f) * c22 + fmaxf(acc[3][o], 0.f) * c23;
        sv_s[(o * TYc + ly) * Wn + lx] = 1.f / (1.f + expf(-s));
    }
    __syncthreads();

    // ---- epilogue: per combo a wave writes 1KB contiguous per stream ----
    const int wv = t >> 6, ln = t & 63;
    const f4* sv4 = reinterpret_cast<const f4*>(sv_s);
    f4* out4 = reinterpret_cast<f4*>(out);
    const size_t totq4 = TOT / 4;
#pragma unroll 1
    for (int combo = wv; combo < Cn * TZc; combo += 4) {
        const int c = combo >> 2, oz = combo & 3;
        const float cav = ca_s[c];
        const f4 v = sv4[oz * 64 + ln];
        const f4 att = v * cav;
        const f4 anti = 1.f - att;
        const size_t off = (((size_t)(b * Cn + c) * DHW) >> 2) +
                           (size_t)(z0 + oz) * (Hn * Wn / 4) +
                           (size_t)y0 * (Wn / 4) + ln;
        __builtin_nontemporal_store(att, &out4[off]);
        __builtin_nontemporal_store(anti, &out4[totq4 + off]);
    }
}

extern "C" void kernel_launch(void* const* d_in, const int* in_sizes, int n_in,
                              void* d_out, int out_size, void* d_ws,
                              size_t ws_size, hipStream_t stream) {
    const float* x = (const float*)d_in[0];
    const float* fc1_w = (const float*)d_in[1];
    const float* fc1_b = (const float*)d_in[2];
    const float* fc2_w = (const float*)d_in[3];
    const float* fc2_b = (const float*)d_in[4];
    const float* conv1_w = (const float*)d_in[5];
    const float* conv2_w = (const float*)d_in[6];

    float* ws = (float*)d_ws;
    float* s_avg = ws;                               // B*DHW
    float* s_max = s_avg + (size_t)Bn * DHW;         // B*DHW
    float* part_sum = s_max + (size_t)Bn * DHW;      // B*C*NCHUNK
    float* part_max = part_sum + Bn * Cn * NCHUNK;   // B*C*NCHUNK
    float* ca = part_max + Bn * Cn * NCHUNK;         // B*C
    unsigned* counter = (unsigned*)(ca + Bn * Cn);   // B

    (void)hipMemsetAsync(counter, 0, Bn * sizeof(unsigned), stream);

    reduce_kernel<<<Bn * NCHUNK, 256, 0, stream>>>(
        x, s_avg, s_max, part_sum, part_max, counter, fc1_w, fc1_b, fc2_w,
        fc2_b, ca);
    conv_kernel<<<Bn * 256, 256, 0, stream>>>(ca, s_avg, s_max, conv1_w,
                                              conv2_w, (float*)d_out);
}

// Round 8
// 177.074 us; speedup vs baseline: 1.4909x; 1.4909x over previous
//
#include <hip/hip_runtime.h>
#include <math.h>

#define Bn 4
#define Cn 32
#define Dn 64
#define Hn 64
#define Wn 64
#define DHW (Dn * Hn * Wn)      /* 262144 */
#define TOT (Bn * Cn * DHW)     /* 33554432 */
#define NCHUNK 256              /* spatial chunks per batch in reduce */

typedef float f4 __attribute__((ext_vector_type(4)));

// ============================================================
// Kernel 1: fused reductions (atomic-free, fence-free).
//  - per (b, spatial): mean & max over C  -> s_avg, s_max  [B,DHW]
//  - per (b, c, chunk): partials -> part_sum/part_max [B,C,NCHUNK]
// NOTE (R7 lesson): NO __threadfence here — device-scope fences cost an
// L2 writeback/invalidate PER BLOCK (~170 us across 1024 blocks).
// ============================================================
__global__ __launch_bounds__(256) void reduce_kernel(
    const float* __restrict__ x,
    float* __restrict__ s_avg, float* __restrict__ s_max,
    float* __restrict__ part_sum, float* __restrict__ part_max) {
    const int b = blockIdx.x / NCHUNK;
    const int chunk = blockIdx.x % NCHUNK;
    const int base = chunk * 1024 + threadIdx.x * 4;
    const int lane = threadIdx.x & 63;
    const int wid = threadIdx.x >> 6;

    f4 ssum = {0.f, 0.f, 0.f, 0.f};
    f4 smax = {-INFINITY, -INFINITY, -INFINITY, -INFINITY};
    float tsum[Cn], tmax[Cn];

    const float* xp = x + (size_t)b * Cn * DHW + base;
#pragma unroll
    for (int c = 0; c < Cn; ++c) {
        const f4 v = *reinterpret_cast<const f4*>(xp + (size_t)c * DHW);
        ssum += v;
        smax.x = fmaxf(smax.x, v.x); smax.y = fmaxf(smax.y, v.y);
        smax.z = fmaxf(smax.z, v.z); smax.w = fmaxf(smax.w, v.w);
        tsum[c] = (v.x + v.y) + (v.z + v.w);
        tmax[c] = fmaxf(fmaxf(v.x, v.y), fmaxf(v.z, v.w));
    }

    const f4 av = ssum * (1.f / Cn);
    *reinterpret_cast<f4*>(s_avg + (size_t)b * DHW + base) = av;
    *reinterpret_cast<f4*>(s_max + (size_t)b * DHW + base) = smax;

    __shared__ float redS[4][Cn];
    __shared__ float redM[4][Cn];
#pragma unroll
    for (int c = 0; c < Cn; ++c) {
        float ps = tsum[c], pm = tmax[c];
#pragma unroll
        for (int off = 32; off; off >>= 1) {
            ps += __shfl_xor(ps, off);
            pm = fmaxf(pm, __shfl_xor(pm, off));
        }
        if (lane == 0) { redS[wid][c] = ps; redM[wid][c] = pm; }
    }
    __syncthreads();
    if (threadIdx.x < Cn) {
        const int c = threadIdx.x;
        float s = (redS[0][c] + redS[1][c]) + (redS[2][c] + redS[3][c]);
        float m = fmaxf(fmaxf(redM[0][c], redM[1][c]),
                        fmaxf(redM[2][c], redM[3][c]));
        part_sum[(b * Cn + c) * NCHUNK + chunk] = s;
        part_max[(b * Cn + c) * NCHUNK + chunk] = m;
    }
}

// ============================================================
// Kernel 2: partial-reduce + channel-attention MLP. 1 block, 256 threads.
// ============================================================
__global__ __launch_bounds__(256) void ca_kernel(
    const float* __restrict__ part_sum, const float* __restrict__ part_max,
    const float* __restrict__ fc1_w, const float* __restrict__ fc1_b,
    const float* __restrict__ fc2_w, const float* __restrict__ fc2_b,
    float* __restrict__ ca) {
    __shared__ float inpAll[Bn][64];
    __shared__ float h[128];
    const int t = threadIdx.x;
    {
        const int which = t >> 7;        // 0: sum, 1: max
        const int b = (t >> 5) & 3;
        const int c = t & 31;
        const f4* p4 = reinterpret_cast<const f4*>(
            (which ? part_max : part_sum) + (b * Cn + c) * NCHUNK);
        if (which == 0) {
            float acc = 0.f;
#pragma unroll
            for (int i = 0; i < NCHUNK / 4; ++i) {
                f4 v = p4[i];
                acc += (v.x + v.y) + (v.z + v.w);
            }
            inpAll[b][c] = acc * (1.f / DHW);
        } else {
            float m = -INFINITY;
#pragma unroll
            for (int i = 0; i < NCHUNK / 4; ++i) {
                f4 v = p4[i];
                m = fmaxf(m, fmaxf(fmaxf(v.x, v.y), fmaxf(v.z, v.w)));
            }
            inpAll[b][Cn + c] = m;
        }
    }
    __syncthreads();
#pragma unroll 1
    for (int b = 0; b < Bn; ++b) {
        if (t < 128) {
            float acc = fc1_b[t];
#pragma unroll
            for (int k = 0; k < 64; ++k) acc += fc1_w[t * 64 + k] * inpAll[b][k];
            h[t] = fmaxf(acc, 0.f);
        }
        __syncthreads();
        if (t < Cn) {
            float a2 = fc2_b[t];
#pragma unroll
            for (int k = 0; k < 128; ++k) a2 += fc2_w[t * 128 + k] * h[k];
            ca[b * Cn + t] = 1.f / (1.f + expf(-a2));
        }
        __syncthreads();
    }
}

// ============================================================
// Kernel 3: conv + epilogue, fused.  (measured ~70 us in R6/R7 - keep)
//  Tile 64x * 4y * 4z; BOTH input-channel halos resident in LDS (56 KB).
//  Writes: per (c,oz) combo a wave stores 1KB contiguous x2 streams, NT.
// ============================================================
#define TZc 4
#define TYc 4
#define LXc (Wn + 6)   /* 70 */
#define LYc (TYc + 6)  /* 10 */
#define LZc (TZc + 6)  /* 10 */
#define HALO1 (LZc * LYc * LXc)  /* 7000 */

__global__ __launch_bounds__(256) void conv_kernel(
    const float* __restrict__ ca_g,
    const float* __restrict__ s_avg, const float* __restrict__ s_max,
    const float* __restrict__ w1, const float* __restrict__ w2,
    float* __restrict__ out) {
    __shared__ float sIn[2 * HALO1];          // 56 KB
    __shared__ float sv_s[TZc * TYc * Wn];    // 1024 floats, 4 KB
    __shared__ float ca_s[Cn];

    const int t = threadIdx.x;
    const int bid = blockIdx.x;
    const int b = bid >> 8;            // 256 tiles per batch
    const int tile = bid & 255;
    const int tz = tile >> 4, ty = tile & 15;
    const int z0 = tz * TZc, y0 = ty * TYc;

    if (t < Cn) ca_s[t] = ca_g[b * Cn + t];

    // ---- load both halo buffers ----
    const float* srcA = s_avg + (size_t)b * DHW;
    const float* srcM = s_max + (size_t)b * DHW;
    for (int i = t; i < 2 * HALO1; i += 256) {
        const int ic = i / HALO1;
        const int r0 = i - ic * HALO1;
        const int xx = r0 % LXc;
        const int rem = r0 / LXc;
        const int yy = rem % LYc;
        const int zz = rem / LYc;
        const int gz = z0 + zz - 3, gy = y0 + yy - 3, gx = xx - 3;
        float v = 0.f;
        if ((unsigned)gz < (unsigned)Dn && (unsigned)gy < (unsigned)Hn &&
            (unsigned)gx < (unsigned)Wn)
            v = (ic ? srcM : srcA)[(gz * Hn + gy) * Wn + gx];
        sIn[i] = v;
    }
    __syncthreads();

    // ---- compute: thread (lx, ly) owns full z-column of 4 outputs ----
    const int lx = t & 63, ly = t >> 6;

    float acc[4][TZc];  // [oc][oz]
#pragma unroll
    for (int oc = 0; oc < 4; ++oc)
#pragma unroll
        for (int o = 0; o < TZc; ++o) acc[oc][o] = 0.f;

#pragma unroll 1
    for (int ic = 0; ic < 2; ++ic)
#pragma unroll 1
        for (int kh = 0; kh < 7; ++kh)
#pragma unroll 1
            for (int kw = 0; kw < 7; ++kw) {
                float incol[LZc];
#pragma unroll
                for (int s = 0; s < LZc; ++s)
                    incol[s] = sIn[ic * HALO1 +
                                   (s * LYc + (ly + kh)) * LXc + (lx + kw)];
#pragma unroll
                for (int kd = 0; kd < 7; ++kd)
#pragma unroll
                    for (int oc = 0; oc < 4; ++oc) {
                        // wave-uniform address -> scalar load
                        float w = w1[(((oc * 2 + ic) * 7 + kd) * 7 + kh) * 7 + kw];
#pragma unroll
                        for (int o = 0; o < TZc; ++o)
                            acc[oc][o] += incol[o + kd] * w;
                    }
            }

    const float c20 = w2[0], c21 = w2[1], c22 = w2[2], c23 = w2[3];
#pragma unroll
    for (int o = 0; o < TZc; ++o) {
        float s = fmaxf(acc[0][o], 0.f) * c20 + fmaxf(acc[1][o], 0.f) * c21 +
                  fmaxf(acc[2][o], 0.f) * c22 + fmaxf(acc[3][o], 0.f) * c23;
        sv_s[(o * TYc + ly) * Wn + lx] = 1.f / (1.f + expf(-s));
    }
    __syncthreads();

    // ---- epilogue: per combo a wave writes 1KB contiguous per stream ----
    const int wv = t >> 6, ln = t & 63;
    const f4* sv4 = reinterpret_cast<const f4*>(sv_s);
    f4* out4 = reinterpret_cast<f4*>(out);
    const size_t totq4 = TOT / 4;
#pragma unroll 1
    for (int combo = wv; combo < Cn * TZc; combo += 4) {
        const int c = combo >> 2, oz = combo & 3;
        const float cav = ca_s[c];
        const f4 v = sv4[oz * 64 + ln];
        const f4 att = v * cav;
        const f4 anti = 1.f - att;
        const size_t off = (((size_t)(b * Cn + c) * DHW) >> 2) +
                           (size_t)(z0 + oz) * (Hn * Wn / 4) +
                           (size_t)y0 * (Wn / 4) + ln;
        __builtin_nontemporal_store(att, &out4[off]);
        __builtin_nontemporal_store(anti, &out4[totq4 + off]);
    }
}

extern "C" void kernel_launch(void* const* d_in, const int* in_sizes, int n_in,
                              void* d_out, int out_size, void* d_ws,
                              size_t ws_size, hipStream_t stream) {
    const float* x = (const float*)d_in[0];
    const float* fc1_w = (const float*)d_in[1];
    const float* fc1_b = (const float*)d_in[2];
    const float* fc2_w = (const float*)d_in[3];
    const float* fc2_b = (const float*)d_in[4];
    const float* conv1_w = (const float*)d_in[5];
    const float* conv2_w = (const float*)d_in[6];

    float* ws = (float*)d_ws;
    float* s_avg = ws;                               // B*DHW
    float* s_max = s_avg + (size_t)Bn * DHW;         // B*DHW
    float* part_sum = s_max + (size_t)Bn * DHW;      // B*C*NCHUNK
    float* part_max = part_sum + Bn * Cn * NCHUNK;   // B*C*NCHUNK
    float* ca = part_max + Bn * Cn * NCHUNK;         // B*C

    reduce_kernel<<<Bn * NCHUNK, 256, 0, stream>>>(x, s_avg, s_max, part_sum,
                                                   part_max);
    ca_kernel<<<1, 256, 0, stream>>>(part_sum, part_max, fc1_w, fc1_b, fc2_w,
                                     fc2_b, ca);
    conv_kernel<<<Bn * 256, 256, 0, stream>>>(ca, s_avg, s_max, conv1_w,
                                              conv2_w, (float*)d_out);
}